// Round 5
// baseline (1284.187 us; speedup 1.0000x reference)
//
#include <hip/hip_runtime.h>
#include <hip/hip_fp16.h>
#include <hip/hip_cooperative_groups.h>
#include <math.h>

namespace cg = cooperative_groups;

// ---------------------------------------------------------------------------
// Whole PointTransformerNet forward in ONE cooperative kernel (8 grid syncs),
// eliminating the ~150us of inter-dispatch overhead measured in R3.
//
// Math identities (verified R2/R3):
//  (1) a_dst cancels in the per-(dst,channel) segment softmax -> no W_dst.
//  (2) delta = d_i - c_j with c_j = pos_j@Wpos folded into the gather payload.
//  (3) b_pos is segment-constant -> cancels in the softmax exponent (kept in
//      the value term). Payload stores (a_src+c)*log2e so the per-edge exp is
//      a bare v_exp_f32.
//  (4) exponent ~ N(0,~3)*1.44, |x| << 128 -> raw exp2, no online max.
//
// R4 bug fixed here: the fused head used __shfl(hval,k) INSIDE the divergent
// `if (lane<32)` branch; ds_bpermute reads from inactive source lanes are
// UNDEFINED on CDNA -> half the fc1 dot product was garbage (absmax 4.36).
// Restored R3's proven pattern: all 64 lanes write hval to LDS first, then
// lanes<32 read it back.
// ---------------------------------------------------------------------------

#define LOG2E 1.44269504088896340736f

struct Params {
    const float* x; const float* pos; const int* src; const int* dst;
    const float* W1_src; const float* W1_val; const float* W1_pos; const float* b1_pos;
    const float* W2_src; const float* W2_val; const float* W2_pos; const float* b2_pos;
    const float* Wfc1; const float* bfc1; const float* Wfc2; const float* bfc2;
    int* count; int* offsets; int* blocksum; int* rank; int* sorted_src;
    __half2* g; float* h; float* out;
    int N, E;
};

__device__ __forceinline__ void eacc(float d2, float dv, __half2 gh,
                                     float& s, float& num) {
    float ax = __low2float(gh);    // (a_src + c) * log2e
    float vv = __high2float(gh);   // v - c
    float ev = exp2f(d2 - ax);     // v_exp_f32
    s += ev;
    num = fmaf(ev, vv + dv, num);
}

// Per-node segment softmax + weighted sum; returns relu'd channel value.
__device__ __forceinline__ float edge_node(
        int node, int laneoff,
        const int* __restrict__ offsets, const int* __restrict__ sorted_src,
        const char* __restrict__ gbase, float d2, float dv) {
    int beg = offsets[node], end = offsets[node + 1];
    float s0 = 0.f, n0 = 0.f, s1 = 0.f, n1 = 0.f;
    int e = beg;
    int aligned = min((beg + 3) & ~3, end);    // peel to 16B alignment
    for (; e < aligned; ++e) {
        int i0 = __builtin_amdgcn_readfirstlane(sorted_src[e]);
        __half2 g0 = *(const __half2*)(gbase + (((size_t)(unsigned)i0) << 8) + laneoff);
        eacc(d2, dv, g0, s0, n0);
    }
    for (; e + 4 <= end; e += 4) {
        int4 ii = *(const int4*)(sorted_src + e);      // one uniform 16B load
        int i0 = __builtin_amdgcn_readfirstlane(ii.x);
        int i1 = __builtin_amdgcn_readfirstlane(ii.y);
        int i2 = __builtin_amdgcn_readfirstlane(ii.z);
        int i3 = __builtin_amdgcn_readfirstlane(ii.w);
        // uniform base + lane*4: address math on the scalar pipe, 4 in flight
        __half2 g0 = *(const __half2*)(gbase + (((size_t)(unsigned)i0) << 8) + laneoff);
        __half2 g1 = *(const __half2*)(gbase + (((size_t)(unsigned)i1) << 8) + laneoff);
        __half2 g2 = *(const __half2*)(gbase + (((size_t)(unsigned)i2) << 8) + laneoff);
        __half2 g3 = *(const __half2*)(gbase + (((size_t)(unsigned)i3) << 8) + laneoff);
        eacc(d2, dv, g0, s0, n0);
        eacc(d2, dv, g1, s1, n1);
        eacc(d2, dv, g2, s0, n0);
        eacc(d2, dv, g3, s1, n1);
    }
    for (; e < end; ++e) {
        int i0 = __builtin_amdgcn_readfirstlane(sorted_src[e]);
        __half2 g0 = *(const __half2*)(gbase + (((size_t)(unsigned)i0) << 8) + laneoff);
        eacc(d2, dv, g0, s0, n0);
    }
    return fmaxf((n0 + n1) / (s0 + s1 + 1e-16f), 0.f);
}

__global__ void __launch_bounds__(256, 8) mega_kernel(Params P) {
    cg::grid_group grid = cg::this_grid();
    __shared__ __half2 Wsh2[4096];   // proj2: (W2_src, W2_val) interleaved, 16KB
    __shared__ float hsh[4][64];     // head: per-wave h broadcast (all-lane write)
    __shared__ int wpre[4];          // scan phase B

    const int tid  = threadIdx.x;
    const int lane = tid & 63;
    const int wid  = tid >> 6;
    const int gtid = blockIdx.x * 256 + tid;
    const int gsz  = gridDim.x * 256;
    const int N = P.N, E = P.E;
    const int nsb = (N + 31) >> 5;          // 32-node scan chunks
    const int laneoff = lane * 4;
    const char* gbase = (const char*)P.g;

    // --- Z: zero the histogram ---
    for (int i = gtid; i < N; i += gsz) P.count[i] = 0;
    grid.sync();

    // --- H: histogram + within-bucket rank (1 atomic/edge) ---
    for (int e = gtid; e < E; e += gsz)
        P.rank[e] = atomicAdd(&P.count[P.dst[e]], 1);
    // --- P1 (independent): conv1 payload g = half2((a_src+c)*log2e, v-c) ---
    for (int t = gtid; t < N * 64; t += gsz) {
        int node = t >> 6, c = t & 63;
        float x0 = P.x[node * 3 + 0], x1 = P.x[node * 3 + 1], x2 = P.x[node * 3 + 2];
        float p0 = P.pos[node * 3 + 0], p1 = P.pos[node * 3 + 1], p2 = P.pos[node * 3 + 2];
        float as = fmaf(x0, P.W1_src[c], fmaf(x1, P.W1_src[64 + c], x2 * P.W1_src[128 + c]));
        float vv = fmaf(x0, P.W1_val[c], fmaf(x1, P.W1_val[64 + c], x2 * P.W1_val[128 + c]));
        float cc = fmaf(p0, P.W1_pos[c], fmaf(p1, P.W1_pos[64 + c], p2 * P.W1_pos[128 + c]));
        P.g[t] = __floats2half2_rn((as + cc) * LOG2E, vv - cc);
    }
    grid.sync();

    // --- S1: per-chunk (32 nodes) local exclusive scan, chunk totals ---
    for (int vb = blockIdx.x; vb < nsb; vb += gridDim.x) {
        if (tid < 64) {
            int idx = vb * 32 + lane;
            int v = (lane < 32 && idx < N) ? P.count[idx] : 0;
            int inc = v;
            #pragma unroll
            for (int off = 1; off < 32; off <<= 1) {
                int t2 = __shfl_up(inc, off);
                if (lane >= off) inc += t2;
            }
            if (lane < 32 && idx < N) P.offsets[idx] = inc - v;
            if (lane == 31) P.blocksum[vb] = inc;
        }
    }
    grid.sync();

    // --- S2: block 0 scans <=2048 chunk totals (8/thread) ---
    if (blockIdx.x == 0) {
        int b8 = tid * 8;
        int v[8], s = 0;
        #pragma unroll
        for (int j = 0; j < 8; ++j) {
            v[j] = (b8 + j < nsb) ? P.blocksum[b8 + j] : 0;
            s += v[j];
        }
        int inc = s;
        #pragma unroll
        for (int off = 1; off < 64; off <<= 1) {
            int t2 = __shfl_up(inc, off);
            if (lane >= off) inc += t2;
        }
        if (lane == 63) wpre[wid] = inc;
        __syncthreads();
        int wbase = 0;
        for (int q = 0; q < wid; ++q) wbase += wpre[q];
        int run = wbase + inc - s;
        #pragma unroll
        for (int j = 0; j < 8; ++j) {
            int tmp = v[j];
            if (b8 + j < nsb) P.blocksum[b8 + j] = run;
            run += tmp;
        }
        if (tid == 255) P.offsets[N] = run;   // grand total = E
    }
    grid.sync();

    // --- S3: add chunk bases -> final CSR offsets ---
    for (int vb = blockIdx.x; vb < nsb; vb += gridDim.x) {
        if (tid < 32) {
            int idx = vb * 32 + tid;
            if (idx < N) P.offsets[idx] += P.blocksum[vb];
        }
    }
    grid.sync();

    // --- SC: atomic-free scatter ---
    for (int e = gtid; e < E; e += gsz)
        P.sorted_src[P.offsets[P.dst[e]] + P.rank[e]] = P.src[e];
    grid.sync();

    const int wslot = blockIdx.x * 4 + wid;
    const int nw = gridDim.x * 4;

    // --- E1: conv1 edge phase (wave per node) ---
    {
        float wp0 = P.W1_pos[lane], wp1 = P.W1_pos[64 + lane], wp2 = P.W1_pos[128 + lane];
        float bp = P.b1_pos[lane];
        for (int node = wslot; node < N; node += nw) {
            float p0 = P.pos[node * 3 + 0], p1 = P.pos[node * 3 + 1], p2 = P.pos[node * 3 + 2];
            float dpos = fmaf(p0, wp0, fmaf(p1, wp1, p2 * wp2));
            float hval = edge_node(node, laneoff, P.offsets, P.sorted_src, gbase,
                                   dpos * LOG2E, dpos + bp);
            P.h[node * 64 + lane] = hval;
        }
    }
    grid.sync();

    // --- P2: conv2 payload; W pair staged in LDS as half2 ---
    for (int idx = tid; idx < 4096; idx += 256)
        Wsh2[idx] = __floats2half2_rn(P.W2_src[idx], P.W2_val[idx]);
    __syncthreads();
    {
        float wp0 = P.W2_pos[lane], wp1 = P.W2_pos[64 + lane], wp2 = P.W2_pos[128 + lane];
        for (int node = wslot; node < N; node += nw) {
            float hval = P.h[node * 64 + lane];
            float as = 0.f, vv = 0.f;
            #pragma unroll 16
            for (int k = 0; k < 64; ++k) {
                float hk = __shfl(hval, k);            // all lanes active: defined
                float2 wk = __half22float2(Wsh2[k * 64 + lane]);
                as = fmaf(hk, wk.x, as);
                vv = fmaf(hk, wk.y, vv);
            }
            float p0 = P.pos[node * 3 + 0], p1 = P.pos[node * 3 + 1], p2 = P.pos[node * 3 + 2];
            float cc = fmaf(p0, wp0, fmaf(p1, wp1, p2 * wp2));
            P.g[node * 64 + lane] = __floats2half2_rn((as + cc) * LOG2E, vv - cc);
        }
    }
    grid.sync();

    // --- E2: conv2 edge phase + fused relu/fc1/relu/fc2 head ---
    {
        float wp0 = P.W2_pos[lane], wp1 = P.W2_pos[64 + lane], wp2 = P.W2_pos[128 + lane];
        float bp = P.b2_pos[lane];
        for (int node = wslot; node < N; node += nw) {
            float p0 = P.pos[node * 3 + 0], p1 = P.pos[node * 3 + 1], p2 = P.pos[node * 3 + 2];
            float dpos = fmaf(p0, wp0, fmaf(p1, wp1, p2 * wp2));
            float hval = edge_node(node, laneoff, P.offsets, P.sorted_src, gbase,
                                   dpos * LOG2E, dpos + bp);
            // R3-proven head: all 64 lanes publish hval to LDS, THEN diverge.
            hsh[wid][lane] = hval;                    // same-wave LDS round-trip
            float t2 = 0.f;
            if (lane < 32) {
                #pragma unroll 16
                for (int k = 0; k < 64; ++k)
                    t2 = fmaf(hsh[wid][k], P.Wfc1[k * 32 + lane], t2);
                t2 = fmaxf(t2 + P.bfc1[lane], 0.f) * P.Wfc2[lane];
            }
            #pragma unroll
            for (int off = 32; off >= 1; off >>= 1) t2 += __shfl_down(t2, off);
            if (lane == 0) P.out[node] = t2 + P.bfc2[0];
        }
    }
}

extern "C" void kernel_launch(void* const* d_in, const int* in_sizes, int n_in,
                              void* d_out, int out_size, void* d_ws, size_t ws_size,
                              hipStream_t stream) {
    const int N = in_sizes[0] / 3;
    const int E = in_sizes[2] / 2;
    const int* eidx = (const int*)d_in[2];

    char* w = (char*)d_ws;
    auto carve = [&](size_t bytes) -> void* {
        void* p = (void*)w;
        w += (bytes + 255) & ~size_t(255);
        return p;
    };

    Params P;
    P.x = (const float*)d_in[0];
    P.pos = (const float*)d_in[1];
    P.src = eidx;
    P.dst = eidx + E;
    P.W1_src = (const float*)d_in[4];
    // d_in[5] = W1_dst: cancels in softmax, unused
    P.W1_val = (const float*)d_in[6];
    P.W1_pos = (const float*)d_in[7];
    P.b1_pos = (const float*)d_in[8];
    P.W2_src = (const float*)d_in[9];
    // d_in[10] = W2_dst: cancels in softmax, unused
    P.W2_val = (const float*)d_in[11];
    P.W2_pos = (const float*)d_in[12];
    P.b2_pos = (const float*)d_in[13];
    P.Wfc1 = (const float*)d_in[14];
    P.bfc1 = (const float*)d_in[15];
    P.Wfc2 = (const float*)d_in[16];
    P.bfc2 = (const float*)d_in[17];
    P.count      = (int*)carve((size_t)N * 4);
    P.offsets    = (int*)carve((size_t)(N + 1) * 4);
    P.blocksum   = (int*)carve((size_t)2048 * 4);
    P.rank       = (int*)carve((size_t)E * 4);
    P.sorted_src = (int*)carve((size_t)E * 4);
    P.g          = (__half2*)carve((size_t)N * 64 * 4);
    P.h          = (float*)carve((size_t)N * 64 * 4);
    P.out = (float*)d_out;
    P.N = N;
    P.E = E;

    // Occupancy-clamped cooperative grid: guarantees co-residency for grid.sync.
    int maxb = 1;
    if (hipOccupancyMaxActiveBlocksPerMultiprocessor(
            &maxb, (const void*)mega_kernel, 256, 0) != hipSuccess || maxb < 1)
        maxb = 1;
    int grid = maxb * 256;           // 256 CUs on MI355X
    if (grid > 2048) grid = 2048;    // 8 blocks/CU cap (32 waves/CU)

    void* args[] = { (void*)&P };
    hipLaunchCooperativeKernel((const void*)mega_kernel, dim3(grid), dim3(256),
                               args, 0, stream);
}

// Round 6
// 287.644 us; speedup vs baseline: 4.4645x; 4.4645x over previous
//
#include <hip/hip_runtime.h>
#include <hip/hip_fp16.h>
#include <math.h>

// ---------------------------------------------------------------------------
// PointTransformerNet forward, 7 graph nodes (R5's cooperative mega-kernel
// regressed 5x: grid.sync on gfx950 = device-scope fence across 8 non-coherent
// XCD L2s, ~200us each. Multi-kernel + graph replay is the right structure.)
//
//   memset(count) ; hist+proj1 ; scan_sum ; scan_emit(inline base) ; scatter ;
//   E1+proj2 fused ; E2+head
//
// Math identities (verified R2-R5):
//  (1) a_dst cancels in the per-(dst,channel) segment softmax -> no W_dst.
//  (2) delta = d_i - c_j, c_j = pos_j@Wpos folded into the gather payload.
//  (3) b_pos cancels in the exponent (kept in value term); payload stores
//      (a_src+c)*log2e so the per-edge exp is a bare v_exp_f32.
//  (4) exponent is small -> raw exp2, no online max.
//  (5) E1+proj2 fuse: proj2 needs only h[node], which E1 ends with in
//      registers (lane=channel) -> no h round-trip, no extra launch.
//
// Edge phase: wave per dst node, lane=channel, 8-deep pipelined 256B gathers
// with scalar address math (uniform base + lane*4).
// ---------------------------------------------------------------------------

#define LOG2E 1.44269504088896340736f

__global__ void __launch_bounds__(256) hist_proj1_kernel(
        const int* __restrict__ dst, int* __restrict__ count, int* __restrict__ rank,
        const float* __restrict__ x, const float* __restrict__ pos,
        const float* __restrict__ W1_src, const float* __restrict__ W1_val,
        const float* __restrict__ W1_pos,
        __half2* __restrict__ g1, int N, int E) {
    int gtid = blockIdx.x * 256 + threadIdx.x;
    int gsz = gridDim.x * 256;
    for (int e = gtid; e < E; e += gsz)
        rank[e] = atomicAdd(&count[dst[e]], 1);
    for (int t = gtid; t < N * 64; t += gsz) {
        int node = t >> 6, c = t & 63;
        float x0 = x[node * 3 + 0], x1 = x[node * 3 + 1], x2 = x[node * 3 + 2];
        float p0 = pos[node * 3 + 0], p1 = pos[node * 3 + 1], p2 = pos[node * 3 + 2];
        float as = fmaf(x0, W1_src[c], fmaf(x1, W1_src[64 + c], x2 * W1_src[128 + c]));
        float vv = fmaf(x0, W1_val[c], fmaf(x1, W1_val[64 + c], x2 * W1_val[128 + c]));
        float cc = fmaf(p0, W1_pos[c], fmaf(p1, W1_pos[64 + c], p2 * W1_pos[128 + c]));
        g1[t] = __floats2half2_rn((as + cc) * LOG2E, vv - cc);
    }
}

// Per-block sums of 1024 counts (4/thread via int4).
__global__ void __launch_bounds__(256) scan_sum_kernel(
        const int* __restrict__ count, int* __restrict__ blocksum, int n) {
    __shared__ int wsum[4];
    int tid = threadIdx.x;
    int base = (blockIdx.x * 256 + tid) * 4;
    int s = 0;
    if (base + 3 < n) {
        int4 c = *(const int4*)&count[base];
        s = c.x + c.y + c.z + c.w;
    } else {
        for (int i = base; i < n; ++i) s += count[i];
    }
    #pragma unroll
    for (int off = 32; off >= 1; off >>= 1) s += __shfl_down(s, off);
    int lane = tid & 63, wid = tid >> 6;
    if (lane == 0) wsum[wid] = s;
    __syncthreads();
    if (tid == 0) blocksum[blockIdx.x] = wsum[0] + wsum[1] + wsum[2] + wsum[3];
}

// Emit offsets; every block redundantly wave-scans the <=64 block sums for its
// own base (folds R3's separate phase-B kernel away).
__global__ void __launch_bounds__(256) scan_emit_kernel(
        const int* __restrict__ count, const int* __restrict__ blocksum,
        int* __restrict__ offsets, int n, int nsb) {
    __shared__ int wpre[4];
    __shared__ int sbase[2];
    int tid = threadIdx.x, lane = tid & 63, wid = tid >> 6;
    if (tid < 64) {                      // wave 0: scan block sums
        int v = (lane < nsb) ? blocksum[lane] : 0;
        int inc = v;
        #pragma unroll
        for (int off = 1; off < 64; off <<= 1) {
            int t2 = __shfl_up(inc, off);
            if (lane >= off) inc += t2;
        }
        if (lane == (int)blockIdx.x) sbase[0] = inc - v;   // this block's base
        if (lane == nsb - 1) sbase[1] = inc;               // grand total (=E)
    }
    int base = (blockIdx.x * 256 + tid) * 4;
    int4 c = make_int4(0, 0, 0, 0);
    if (base + 3 < n) {
        c = *(const int4*)&count[base];
    } else {
        if (base + 0 < n) c.x = count[base + 0];
        if (base + 1 < n) c.y = count[base + 1];
        if (base + 2 < n) c.z = count[base + 2];
    }
    int tsum = c.x + c.y + c.z + c.w;
    int inc = tsum;
    #pragma unroll
    for (int off = 1; off < 64; off <<= 1) {
        int t2 = __shfl_up(inc, off);
        if (lane >= off) inc += t2;
    }
    if (lane == 63) wpre[wid] = inc;
    __syncthreads();
    int wbase = 0;
    for (int q = 0; q < wid; ++q) wbase += wpre[q];
    int excl = sbase[0] + wbase + (inc - tsum);
    if (base + 0 < n) offsets[base + 0] = excl;
    if (base + 1 < n) offsets[base + 1] = excl + c.x;
    if (base + 2 < n) offsets[base + 2] = excl + c.x + c.y;
    if (base + 3 < n) offsets[base + 3] = excl + c.x + c.y + c.z;
    if (blockIdx.x == 0 && tid == 0) offsets[n] = sbase[1];
}

__global__ void __launch_bounds__(256) scatter_kernel(
        const int* __restrict__ src, const int* __restrict__ dst,
        const int* __restrict__ rank, const int* __restrict__ offsets,
        int* __restrict__ sorted_src, int E) {
    int e = blockIdx.x * 256 + threadIdx.x;
    if (e < E) sorted_src[offsets[dst[e]] + rank[e]] = src[e];
}

__device__ __forceinline__ void eacc(float d2, float dv, __half2 gh,
                                     float& s, float& num) {
    float ax = __low2float(gh);    // (a_src + c) * log2e
    float vv = __high2float(gh);   // v - c
    float ev = exp2f(d2 - ax);     // bare v_exp_f32
    s += ev;
    num = fmaf(ev, vv + dv, num);
}

// Segment softmax + weighted sum for one node; 8-deep pipelined gathers.
__device__ __forceinline__ float edge_node(
        int node, int laneoff,
        const int* __restrict__ offsets, const int* __restrict__ ss,
        const char* __restrict__ gbase, float d2, float dv) {
    int beg = offsets[node], end = offsets[node + 1];
    float s0 = 0.f, n0 = 0.f, s1 = 0.f, n1 = 0.f;
    int e = beg;
    int aligned = min((beg + 3) & ~3, end);    // peel to 16B alignment
    for (; e < aligned; ++e) {
        int i0 = __builtin_amdgcn_readfirstlane(ss[e]);
        __half2 g0 = *(const __half2*)(gbase + (((size_t)(unsigned)i0) << 8) + laneoff);
        eacc(d2, dv, g0, s0, n0);
    }
    for (; e + 8 <= end; e += 8) {
        int4 ia = *(const int4*)(ss + e);          // two uniform 16B loads
        int4 ib = *(const int4*)(ss + e + 4);
        int i0 = __builtin_amdgcn_readfirstlane(ia.x);
        int i1 = __builtin_amdgcn_readfirstlane(ia.y);
        int i2 = __builtin_amdgcn_readfirstlane(ia.z);
        int i3 = __builtin_amdgcn_readfirstlane(ia.w);
        int i4 = __builtin_amdgcn_readfirstlane(ib.x);
        int i5 = __builtin_amdgcn_readfirstlane(ib.y);
        int i6 = __builtin_amdgcn_readfirstlane(ib.z);
        int i7 = __builtin_amdgcn_readfirstlane(ib.w);
        __half2 g0 = *(const __half2*)(gbase + (((size_t)(unsigned)i0) << 8) + laneoff);
        __half2 g1 = *(const __half2*)(gbase + (((size_t)(unsigned)i1) << 8) + laneoff);
        __half2 g2 = *(const __half2*)(gbase + (((size_t)(unsigned)i2) << 8) + laneoff);
        __half2 g3 = *(const __half2*)(gbase + (((size_t)(unsigned)i3) << 8) + laneoff);
        __half2 g4 = *(const __half2*)(gbase + (((size_t)(unsigned)i4) << 8) + laneoff);
        __half2 g5 = *(const __half2*)(gbase + (((size_t)(unsigned)i5) << 8) + laneoff);
        __half2 g6 = *(const __half2*)(gbase + (((size_t)(unsigned)i6) << 8) + laneoff);
        __half2 g7 = *(const __half2*)(gbase + (((size_t)(unsigned)i7) << 8) + laneoff);
        eacc(d2, dv, g0, s0, n0);
        eacc(d2, dv, g1, s1, n1);
        eacc(d2, dv, g2, s0, n0);
        eacc(d2, dv, g3, s1, n1);
        eacc(d2, dv, g4, s0, n0);
        eacc(d2, dv, g5, s1, n1);
        eacc(d2, dv, g6, s0, n0);
        eacc(d2, dv, g7, s1, n1);
    }
    for (; e + 4 <= end; e += 4) {
        int4 ia = *(const int4*)(ss + e);
        int i0 = __builtin_amdgcn_readfirstlane(ia.x);
        int i1 = __builtin_amdgcn_readfirstlane(ia.y);
        int i2 = __builtin_amdgcn_readfirstlane(ia.z);
        int i3 = __builtin_amdgcn_readfirstlane(ia.w);
        __half2 g0 = *(const __half2*)(gbase + (((size_t)(unsigned)i0) << 8) + laneoff);
        __half2 g1 = *(const __half2*)(gbase + (((size_t)(unsigned)i1) << 8) + laneoff);
        __half2 g2 = *(const __half2*)(gbase + (((size_t)(unsigned)i2) << 8) + laneoff);
        __half2 g3 = *(const __half2*)(gbase + (((size_t)(unsigned)i3) << 8) + laneoff);
        eacc(d2, dv, g0, s0, n0);
        eacc(d2, dv, g1, s1, n1);
        eacc(d2, dv, g2, s0, n0);
        eacc(d2, dv, g3, s1, n1);
    }
    for (; e < end; ++e) {
        int i0 = __builtin_amdgcn_readfirstlane(ss[e]);
        __half2 g0 = *(const __half2*)(gbase + (((size_t)(unsigned)i0) << 8) + laneoff);
        eacc(d2, dv, g0, s0, n0);
    }
    return fmaxf((n0 + n1) / (s0 + s1 + 1e-16f), 0.f);
}

// E1 + proj2 fused: conv1 aggregate (h in registers, lane=channel) feeds the
// conv2 projections directly via __shfl broadcast + LDS-staged W2 pair.
__global__ void __launch_bounds__(256, 8) e1p2_kernel(
        const float* __restrict__ pos,
        const int* __restrict__ offsets, const int* __restrict__ sorted_src,
        const __half2* __restrict__ g1,
        const float* __restrict__ W1_pos, const float* __restrict__ b1_pos,
        const float* __restrict__ W2_src, const float* __restrict__ W2_val,
        const float* __restrict__ W2_pos,
        __half2* __restrict__ g2, int N) {
    __shared__ __half2 Wsh[4096];    // (W2_src, W2_val) interleaved, 16KB
    int tid = threadIdx.x, lane = tid & 63, wid = tid >> 6;
    for (int idx = tid; idx < 4096; idx += 256)
        Wsh[idx] = __floats2half2_rn(W2_src[idx], W2_val[idx]);
    __syncthreads();

    int node = blockIdx.x * 4 + wid;
    if (node >= N) return;

    float p0 = pos[node * 3 + 0], p1 = pos[node * 3 + 1], p2 = pos[node * 3 + 2];
    float dpos = fmaf(p0, W1_pos[lane],
                 fmaf(p1, W1_pos[64 + lane], p2 * W1_pos[128 + lane]));
    float hval = edge_node(node, lane * 4, offsets, sorted_src,
                           (const char*)g1, dpos * LOG2E, dpos + b1_pos[lane]);
    // conv2 projections: h (registers) @ {W2_src, W2_val}
    float as = 0.f, vv = 0.f;
    #pragma unroll 16
    for (int k = 0; k < 64; ++k) {
        float hk = __shfl(hval, k);              // all 64 lanes active: defined
        float2 wk = __half22float2(Wsh[k * 64 + lane]);
        as = fmaf(hk, wk.x, as);
        vv = fmaf(hk, wk.y, vv);
    }
    float cc = fmaf(p0, W2_pos[lane],
               fmaf(p1, W2_pos[64 + lane], p2 * W2_pos[128 + lane]));
    g2[node * 64 + lane] = __floats2half2_rn((as + cc) * LOG2E, vv - cc);
}

// E2 + fused relu/fc1/relu/fc2 head. fc1 uses all 64 lanes:
// lane l -> out channel l&31, k-half l>>5; combine halves via shfl_down(32).
__global__ void __launch_bounds__(256, 8) e2head_kernel(
        const float* __restrict__ pos,
        const int* __restrict__ offsets, const int* __restrict__ sorted_src,
        const __half2* __restrict__ g2,
        const float* __restrict__ W2_pos, const float* __restrict__ b2_pos,
        const float* __restrict__ Wfc1, const float* __restrict__ bfc1,
        const float* __restrict__ Wfc2, const float* __restrict__ bfc2,
        float* __restrict__ out, int N) {
    __shared__ float Wfc1sh[64 * 32];    // 8KB
    __shared__ float hsh[4][64];
    int tid = threadIdx.x, lane = tid & 63, wid = tid >> 6;
    for (int idx = tid; idx < 2048; idx += 256) Wfc1sh[idx] = Wfc1[idx];
    __syncthreads();

    int node = blockIdx.x * 4 + wid;
    if (node >= N) return;

    float p0 = pos[node * 3 + 0], p1 = pos[node * 3 + 1], p2 = pos[node * 3 + 2];
    float dpos = fmaf(p0, W2_pos[lane],
                 fmaf(p1, W2_pos[64 + lane], p2 * W2_pos[128 + lane]));
    float hval = edge_node(node, lane * 4, offsets, sorted_src,
                           (const char*)g2, dpos * LOG2E, dpos + b2_pos[lane]);
    hsh[wid][lane] = hval;               // same-wave LDS publish (all 64 lanes)
    int c = lane & 31, kh = (lane >> 5) * 32;
    float t2 = 0.f;
    #pragma unroll 8
    for (int k = 0; k < 32; ++k)
        t2 = fmaf(hsh[wid][kh + k], Wfc1sh[(kh + k) * 32 + c], t2);
    t2 += __shfl_down(t2, 32);           // all lanes execute; lanes<32 full sum
    t2 = fmaxf(t2 + bfc1[c], 0.f) * Wfc2[c];
    t2 = (lane < 32) ? t2 : 0.f;         // mask upper half, then full reduce
    #pragma unroll
    for (int off = 16; off >= 1; off >>= 1) t2 += __shfl_down(t2, off);
    if (lane == 0) out[node] = t2 + bfc2[0];
}

extern "C" void kernel_launch(void* const* d_in, const int* in_sizes, int n_in,
                              void* d_out, int out_size, void* d_ws, size_t ws_size,
                              hipStream_t stream) {
    const float* x   = (const float*)d_in[0];
    const float* pos = (const float*)d_in[1];
    const int* eidx  = (const int*)d_in[2];
    const float* W1_src = (const float*)d_in[4];
    // d_in[5] = W1_dst: cancels in softmax
    const float* W1_val = (const float*)d_in[6];
    const float* W1_pos = (const float*)d_in[7];
    const float* b1_pos = (const float*)d_in[8];
    const float* W2_src = (const float*)d_in[9];
    // d_in[10] = W2_dst: cancels in softmax
    const float* W2_val = (const float*)d_in[11];
    const float* W2_pos = (const float*)d_in[12];
    const float* b2_pos = (const float*)d_in[13];
    const float* W_fc1  = (const float*)d_in[14];
    const float* b_fc1  = (const float*)d_in[15];
    const float* W_fc2  = (const float*)d_in[16];
    const float* b_fc2  = (const float*)d_in[17];

    const int N = in_sizes[0] / 3;
    const int E = in_sizes[2] / 2;
    const int* src = eidx;
    const int* dst = eidx + E;
    const int nsb = (N + 1023) / 1024;   // 49 for N=50K (must be <=64)

    char* w = (char*)d_ws;
    auto carve = [&](size_t bytes) -> void* {
        void* p = (void*)w;
        w += (bytes + 255) & ~size_t(255);
        return p;
    };
    int*     count      = (int*)carve((size_t)N * 4);
    int*     offsets    = (int*)carve((size_t)(N + 1) * 4);
    int*     blocksum   = (int*)carve((size_t)64 * 4);
    int*     rank       = (int*)carve((size_t)E * 4);
    int*     sorted_src = (int*)carve((size_t)E * 4);
    __half2* g1         = (__half2*)carve((size_t)N * 64 * 4);
    __half2* g2         = (__half2*)carve((size_t)N * 64 * 4);

    hipMemsetAsync(count, 0, (size_t)N * 4, stream);
    hist_proj1_kernel<<<(N * 64 + 255) / 256, 256, 0, stream>>>(
        dst, count, rank, x, pos, W1_src, W1_val, W1_pos, g1, N, E);
    scan_sum_kernel<<<nsb, 256, 0, stream>>>(count, blocksum, N);
    scan_emit_kernel<<<nsb, 256, 0, stream>>>(count, blocksum, offsets, N, nsb);
    scatter_kernel<<<(E + 255) / 256, 256, 0, stream>>>(src, dst, rank, offsets,
                                                        sorted_src, E);
    e1p2_kernel<<<(N + 3) / 4, 256, 0, stream>>>(
        pos, offsets, sorted_src, g1, W1_pos, b1_pos, W2_src, W2_val, W2_pos, g2, N);
    e2head_kernel<<<(N + 3) / 4, 256, 0, stream>>>(
        pos, offsets, sorted_src, g2, W2_pos, b2_pos,
        W_fc1, b_fc1, W_fc2, b_fc2, (float*)d_out, N);
}

// Round 7
// 266.070 us; speedup vs baseline: 4.8265x; 1.0811x over previous
//
#include <hip/hip_runtime.h>
#include <hip/hip_fp16.h>
#include <math.h>

// ---------------------------------------------------------------------------
// PointTransformerNet forward, 6 graph nodes:
//   memset(count) ; hist+proj1 ; scan(single) ; scatter ; E1+proj2 ; E2+head
//
// R6 lesson: e1p2/e2head at 12500 blocks x 4 nodes re-staged LDS weights per
// block (12500 x 16KB) -> 94us. Fix: 2048 grid-strided blocks, weights staged
// once per block, ~24 nodes per wave.
// R5 lesson: grid.sync on gfx950 ~200us each (8 XCD L2 flush) -- never.
//
// Math identities (verified R2-R6):
//  (1) a_dst cancels in the per-(dst,channel) segment softmax -> no W_dst.
//  (2) delta = d_i - c_j, c_j = pos_j@Wpos folded into the gather payload.
//  (3) b_pos cancels in the exponent (kept in value term); payload stores
//      (a_src+c)*log2e so the per-edge exp is a bare v_exp_f32.
//  (4) exponent is small -> raw exp2, no online max.
//  (5) E1+proj2 fuse: proj2 needs only h[node], which E1 holds in registers
//      (lane=channel) -> no h round-trip.
//
// Edge phase: wave per dst node, lane=channel, 8-deep pipelined 256B gathers
// with scalar address math (uniform base + lane*4).
// ---------------------------------------------------------------------------

#define LOG2E 1.44269504088896340736f

__global__ void __launch_bounds__(256) hist_proj1_kernel(
        const int* __restrict__ dst, int* __restrict__ count, int* __restrict__ rank,
        const float* __restrict__ x, const float* __restrict__ pos,
        const float* __restrict__ W1_src, const float* __restrict__ W1_val,
        const float* __restrict__ W1_pos,
        __half2* __restrict__ g1, int N, int E) {
    int gtid = blockIdx.x * 256 + threadIdx.x;
    int gsz = gridDim.x * 256;
    for (int e = gtid; e < E; e += gsz)
        rank[e] = atomicAdd(&count[dst[e]], 1);
    for (int t = gtid; t < N * 64; t += gsz) {
        int node = t >> 6, c = t & 63;
        float x0 = x[node * 3 + 0], x1 = x[node * 3 + 1], x2 = x[node * 3 + 2];
        float p0 = pos[node * 3 + 0], p1 = pos[node * 3 + 1], p2 = pos[node * 3 + 2];
        float as = fmaf(x0, W1_src[c], fmaf(x1, W1_src[64 + c], x2 * W1_src[128 + c]));
        float vv = fmaf(x0, W1_val[c], fmaf(x1, W1_val[64 + c], x2 * W1_val[128 + c]));
        float cc = fmaf(p0, W1_pos[c], fmaf(p1, W1_pos[64 + c], p2 * W1_pos[128 + c]));
        g1[t] = __floats2half2_rn((as + cc) * LOG2E, vv - cc);
    }
}

// Single-kernel scan: block b redundantly reduces count[0 .. b*1024) for its
// base (<=49K ints from L2), then emits its 1024-chunk's exclusive prefix.
__global__ void __launch_bounds__(256) scan_kernel(
        const int* __restrict__ count, int* __restrict__ offsets, int n, int nsb) {
    __shared__ int red[4];
    __shared__ int wpre[4];
    int tid = threadIdx.x, lane = tid & 63, wid = tid >> 6;

    // --- base = sum of all counts before this block's chunk ---
    int lim = blockIdx.x * 1024;           // multiple of 1024, <= n
    int s = 0;
    for (int i = tid * 4; i < lim; i += 1024) {
        int4 c = *(const int4*)&count[i];
        s += c.x + c.y + c.z + c.w;
    }
    #pragma unroll
    for (int off = 32; off >= 1; off >>= 1) s += __shfl_down(s, off);
    if (lane == 0) red[wid] = s;
    __syncthreads();
    int base = red[0] + red[1] + red[2] + red[3];

    // --- local exclusive prefix of this chunk (4 counts/thread) ---
    int b4 = lim + tid * 4;
    int4 c = make_int4(0, 0, 0, 0);
    if (b4 + 3 < n) {
        c = *(const int4*)&count[b4];
    } else {
        if (b4 + 0 < n) c.x = count[b4 + 0];
        if (b4 + 1 < n) c.y = count[b4 + 1];
        if (b4 + 2 < n) c.z = count[b4 + 2];
    }
    int tsum = c.x + c.y + c.z + c.w;
    int inc = tsum;
    #pragma unroll
    for (int off = 1; off < 64; off <<= 1) {
        int t2 = __shfl_up(inc, off);
        if (lane >= off) inc += t2;
    }
    if (lane == 63) wpre[wid] = inc;
    __syncthreads();
    int wbase = 0;
    for (int q = 0; q < wid; ++q) wbase += wpre[q];
    int excl = base + wbase + (inc - tsum);
    if (b4 + 0 < n) offsets[b4 + 0] = excl;
    if (b4 + 1 < n) offsets[b4 + 1] = excl + c.x;
    if (b4 + 2 < n) offsets[b4 + 2] = excl + c.x + c.y;
    if (b4 + 3 < n) offsets[b4 + 3] = excl + c.x + c.y + c.z;
    // last block writes the grand total
    if ((int)blockIdx.x == nsb - 1 && tid == 0)
        offsets[n] = base + wpre[0] + wpre[1] + wpre[2] + wpre[3];
}

__global__ void __launch_bounds__(256) scatter_kernel(
        const int* __restrict__ src, const int* __restrict__ dst,
        const int* __restrict__ rank, const int* __restrict__ offsets,
        int* __restrict__ sorted_src, int E) {
    int e = blockIdx.x * 256 + threadIdx.x;
    if (e < E) sorted_src[offsets[dst[e]] + rank[e]] = src[e];
}

__device__ __forceinline__ void eacc(float d2, float dv, __half2 gh,
                                     float& s, float& num) {
    float ax = __low2float(gh);    // (a_src + c) * log2e
    float vv = __high2float(gh);   // v - c
    float ev = exp2f(d2 - ax);     // bare v_exp_f32
    s += ev;
    num = fmaf(ev, vv + dv, num);
}

// Segment softmax + weighted sum for one node; 8-deep pipelined gathers.
__device__ __forceinline__ float edge_node(
        int node, int laneoff,
        const int* __restrict__ offsets, const int* __restrict__ ss,
        const char* __restrict__ gbase, float d2, float dv) {
    int beg = offsets[node], end = offsets[node + 1];
    float s0 = 0.f, n0 = 0.f, s1 = 0.f, n1 = 0.f;
    int e = beg;
    int aligned = min((beg + 3) & ~3, end);    // peel to 16B alignment
    for (; e < aligned; ++e) {
        int i0 = __builtin_amdgcn_readfirstlane(ss[e]);
        __half2 g0 = *(const __half2*)(gbase + (((size_t)(unsigned)i0) << 8) + laneoff);
        eacc(d2, dv, g0, s0, n0);
    }
    for (; e + 8 <= end; e += 8) {
        int4 ia = *(const int4*)(ss + e);          // two uniform 16B loads
        int4 ib = *(const int4*)(ss + e + 4);
        int i0 = __builtin_amdgcn_readfirstlane(ia.x);
        int i1 = __builtin_amdgcn_readfirstlane(ia.y);
        int i2 = __builtin_amdgcn_readfirstlane(ia.z);
        int i3 = __builtin_amdgcn_readfirstlane(ia.w);
        int i4 = __builtin_amdgcn_readfirstlane(ib.x);
        int i5 = __builtin_amdgcn_readfirstlane(ib.y);
        int i6 = __builtin_amdgcn_readfirstlane(ib.z);
        int i7 = __builtin_amdgcn_readfirstlane(ib.w);
        __half2 g0 = *(const __half2*)(gbase + (((size_t)(unsigned)i0) << 8) + laneoff);
        __half2 g1 = *(const __half2*)(gbase + (((size_t)(unsigned)i1) << 8) + laneoff);
        __half2 g2 = *(const __half2*)(gbase + (((size_t)(unsigned)i2) << 8) + laneoff);
        __half2 g3 = *(const __half2*)(gbase + (((size_t)(unsigned)i3) << 8) + laneoff);
        __half2 g4 = *(const __half2*)(gbase + (((size_t)(unsigned)i4) << 8) + laneoff);
        __half2 g5 = *(const __half2*)(gbase + (((size_t)(unsigned)i5) << 8) + laneoff);
        __half2 g6 = *(const __half2*)(gbase + (((size_t)(unsigned)i6) << 8) + laneoff);
        __half2 g7 = *(const __half2*)(gbase + (((size_t)(unsigned)i7) << 8) + laneoff);
        eacc(d2, dv, g0, s0, n0);
        eacc(d2, dv, g1, s1, n1);
        eacc(d2, dv, g2, s0, n0);
        eacc(d2, dv, g3, s1, n1);
        eacc(d2, dv, g4, s0, n0);
        eacc(d2, dv, g5, s1, n1);
        eacc(d2, dv, g6, s0, n0);
        eacc(d2, dv, g7, s1, n1);
    }
    for (; e + 4 <= end; e += 4) {
        int4 ia = *(const int4*)(ss + e);
        int i0 = __builtin_amdgcn_readfirstlane(ia.x);
        int i1 = __builtin_amdgcn_readfirstlane(ia.y);
        int i2 = __builtin_amdgcn_readfirstlane(ia.z);
        int i3 = __builtin_amdgcn_readfirstlane(ia.w);
        __half2 g0 = *(const __half2*)(gbase + (((size_t)(unsigned)i0) << 8) + laneoff);
        __half2 g1 = *(const __half2*)(gbase + (((size_t)(unsigned)i1) << 8) + laneoff);
        __half2 g2 = *(const __half2*)(gbase + (((size_t)(unsigned)i2) << 8) + laneoff);
        __half2 g3 = *(const __half2*)(gbase + (((size_t)(unsigned)i3) << 8) + laneoff);
        eacc(d2, dv, g0, s0, n0);
        eacc(d2, dv, g1, s1, n1);
        eacc(d2, dv, g2, s0, n0);
        eacc(d2, dv, g3, s1, n1);
    }
    for (; e < end; ++e) {
        int i0 = __builtin_amdgcn_readfirstlane(ss[e]);
        __half2 g0 = *(const __half2*)(gbase + (((size_t)(unsigned)i0) << 8) + laneoff);
        eacc(d2, dv, g0, s0, n0);
    }
    return fmaxf((n0 + n1) / (s0 + s1 + 1e-16f), 0.f);
}

// E1 + proj2 fused, GRID-STRIDED: W2 pair staged in LDS once per block and
// amortized over ~24 nodes/wave; h stays in registers (lane=channel).
__global__ void __launch_bounds__(256, 8) e1p2_kernel(
        const float* __restrict__ pos,
        const int* __restrict__ offsets, const int* __restrict__ sorted_src,
        const __half2* __restrict__ g1,
        const float* __restrict__ W1_pos, const float* __restrict__ b1_pos,
        const float* __restrict__ W2_src, const float* __restrict__ W2_val,
        const float* __restrict__ W2_pos,
        __half2* __restrict__ g2, int N) {
    __shared__ __half2 Wsh[4096];    // (W2_src, W2_val) interleaved, 16KB
    int tid = threadIdx.x, lane = tid & 63, wid = tid >> 6;
    for (int idx = tid; idx < 4096; idx += 256)
        Wsh[idx] = __floats2half2_rn(W2_src[idx], W2_val[idx]);
    __syncthreads();

    // lane-resident constants hoisted out of the node loop
    float w1p0 = W1_pos[lane], w1p1 = W1_pos[64 + lane], w1p2 = W1_pos[128 + lane];
    float bp1 = b1_pos[lane];
    float w2p0 = W2_pos[lane], w2p1 = W2_pos[64 + lane], w2p2 = W2_pos[128 + lane];
    int laneoff = lane * 4;
    int nwav = gridDim.x * 4;

    for (int node = blockIdx.x * 4 + wid; node < N; node += nwav) {
        float p0 = pos[node * 3 + 0], p1 = pos[node * 3 + 1], p2 = pos[node * 3 + 2];
        float dpos = fmaf(p0, w1p0, fmaf(p1, w1p1, p2 * w1p2));
        float hval = edge_node(node, laneoff, offsets, sorted_src,
                               (const char*)g1, dpos * LOG2E, dpos + bp1);
        // conv2 projections: h (registers) @ {W2_src, W2_val}
        float as = 0.f, vv = 0.f;
        #pragma unroll 16
        for (int k = 0; k < 64; ++k) {
            float hk = __shfl(hval, k);          // all 64 lanes active: defined
            float2 wk = __half22float2(Wsh[k * 64 + lane]);
            as = fmaf(hk, wk.x, as);
            vv = fmaf(hk, wk.y, vv);
        }
        float cc = fmaf(p0, w2p0, fmaf(p1, w2p1, p2 * w2p2));
        g2[node * 64 + lane] = __floats2half2_rn((as + cc) * LOG2E, vv - cc);
    }
}

// E2 + fused relu/fc1/relu/fc2 head, GRID-STRIDED. fc1 uses all 64 lanes:
// lane l -> out channel l&31, k-half l>>5; halves combined via shfl_down(32).
__global__ void __launch_bounds__(256, 8) e2head_kernel(
        const float* __restrict__ pos,
        const int* __restrict__ offsets, const int* __restrict__ sorted_src,
        const __half2* __restrict__ g2,
        const float* __restrict__ W2_pos, const float* __restrict__ b2_pos,
        const float* __restrict__ Wfc1, const float* __restrict__ bfc1,
        const float* __restrict__ Wfc2, const float* __restrict__ bfc2,
        float* __restrict__ out, int N) {
    __shared__ float Wfc1sh[64 * 32];    // 8KB, staged once per block
    __shared__ float hsh[4][64];
    int tid = threadIdx.x, lane = tid & 63, wid = tid >> 6;
    for (int idx = tid; idx < 2048; idx += 256) Wfc1sh[idx] = Wfc1[idx];
    __syncthreads();

    float wp0 = W2_pos[lane], wp1 = W2_pos[64 + lane], wp2 = W2_pos[128 + lane];
    float bp = b2_pos[lane];
    int c = lane & 31, kh = (lane >> 5) * 32;
    float bfc1c = bfc1[c], wfc2c = Wfc2[c], bias2 = bfc2[0];
    int laneoff = lane * 4;
    int nwav = gridDim.x * 4;

    for (int node = blockIdx.x * 4 + wid; node < N; node += nwav) {
        float p0 = pos[node * 3 + 0], p1 = pos[node * 3 + 1], p2 = pos[node * 3 + 2];
        float dpos = fmaf(p0, wp0, fmaf(p1, wp1, p2 * wp2));
        float hval = edge_node(node, laneoff, offsets, sorted_src,
                               (const char*)g2, dpos * LOG2E, dpos + bp);
        hsh[wid][lane] = hval;           // same-wave LDS publish (all 64 lanes)
        float t2 = 0.f;
        #pragma unroll 8
        for (int k = 0; k < 32; ++k)
            t2 = fmaf(hsh[wid][kh + k], Wfc1sh[(kh + k) * 32 + c], t2);
        t2 += __shfl_down(t2, 32);       // all lanes execute; lanes<32 full sum
        t2 = fmaxf(t2 + bfc1c, 0.f) * wfc2c;
        t2 = (lane < 32) ? t2 : 0.f;     // mask upper half, then reduce
        #pragma unroll
        for (int off = 16; off >= 1; off >>= 1) t2 += __shfl_down(t2, off);
        if (lane == 0) out[node] = t2 + bias2;
    }
}

extern "C" void kernel_launch(void* const* d_in, const int* in_sizes, int n_in,
                              void* d_out, int out_size, void* d_ws, size_t ws_size,
                              hipStream_t stream) {
    const float* x   = (const float*)d_in[0];
    const float* pos = (const float*)d_in[1];
    const int* eidx  = (const int*)d_in[2];
    const float* W1_src = (const float*)d_in[4];
    // d_in[5] = W1_dst: cancels in softmax
    const float* W1_val = (const float*)d_in[6];
    const float* W1_pos = (const float*)d_in[7];
    const float* b1_pos = (const float*)d_in[8];
    const float* W2_src = (const float*)d_in[9];
    // d_in[10] = W2_dst: cancels in softmax
    const float* W2_val = (const float*)d_in[11];
    const float* W2_pos = (const float*)d_in[12];
    const float* b2_pos = (const float*)d_in[13];
    const float* W_fc1  = (const float*)d_in[14];
    const float* b_fc1  = (const float*)d_in[15];
    const float* W_fc2  = (const float*)d_in[16];
    const float* b_fc2  = (const float*)d_in[17];

    const int N = in_sizes[0] / 3;
    const int E = in_sizes[2] / 2;
    const int* src = eidx;
    const int* dst = eidx + E;
    const int nsb = (N + 1023) / 1024;   // 49 for N=50K

    char* w = (char*)d_ws;
    auto carve = [&](size_t bytes) -> void* {
        void* p = (void*)w;
        w += (bytes + 255) & ~size_t(255);
        return p;
    };
    int*     count      = (int*)carve((size_t)N * 4);
    int*     offsets    = (int*)carve((size_t)(N + 1) * 4);
    int*     rank       = (int*)carve((size_t)E * 4);
    int*     sorted_src = (int*)carve((size_t)E * 4);
    __half2* g1         = (__half2*)carve((size_t)N * 64 * 4);
    __half2* g2         = (__half2*)carve((size_t)N * 64 * 4);

    hipMemsetAsync(count, 0, (size_t)N * 4, stream);
    hist_proj1_kernel<<<(N * 64 + 255) / 256, 256, 0, stream>>>(
        dst, count, rank, x, pos, W1_src, W1_val, W1_pos, g1, N, E);
    scan_kernel<<<nsb, 256, 0, stream>>>(count, offsets, N, nsb);
    scatter_kernel<<<(E + 255) / 256, 256, 0, stream>>>(src, dst, rank, offsets,
                                                        sorted_src, E);
    e1p2_kernel<<<2048, 256, 0, stream>>>(
        pos, offsets, sorted_src, g1, W1_pos, b1_pos, W2_src, W2_val, W2_pos, g2, N);
    e2head_kernel<<<2048, 256, 0, stream>>>(
        pos, offsets, sorted_src, g2, W2_pos, b2_pos,
        W_fc1, b_fc1, W_fc2, b_fc2, (float*)d_out, N);
}

// Round 8
// 246.406 us; speedup vs baseline: 5.2117x; 1.0798x over previous
//
#include <hip/hip_runtime.h>
#include <hip/hip_fp16.h>
#include <math.h>

// ---------------------------------------------------------------------------
// PointTransformerNet forward, 6 kernels + memset:
//   memset(count) ; hist+proj1 ; scan(single) ; scatter ; E1+proj2 ; E2+head
//
// R7 lesson: e1p2 was VALU-issue-bound on the proj2 dot (64x bpermute+cvt+fma
// ~= 190 VALU/node > the edge loop itself). R8: v_dot2_f32_f16 + LDS-packed
// half pairs -> 64 VALU/node for the dot.
// R6 lesson: grid-stride + stage weights once per block (not per 4 nodes).
// R5 lesson: grid.sync on gfx950 ~200us each (8 XCD L2 flush) -- never.
//
// Math identities (verified R2-R7):
//  (1) a_dst cancels in the per-(dst,channel) segment softmax -> no W_dst.
//  (2) delta = d_i - c_j, c_j = pos_j@Wpos folded into the gather payload.
//  (3) b_pos cancels in the exponent; payload stores (a_src+c)*log2e so the
//      per-edge exp is a bare v_exp_f32.
//  (4) exponent is small -> raw exp2, no online max.
//  (5) sum ev*(vv+dv) = nvv + dv*s -> per-edge add hoisted out of the loop.
// ---------------------------------------------------------------------------

#define LOG2E 1.44269504088896340736f

typedef _Float16 hf2 __attribute__((ext_vector_type(2)));
union H2U { __half2 hh; hf2 hf; unsigned u; };
union WPack { uint2 u2; struct { unsigned s, v; } w; };

#if defined(__has_builtin)
#if __has_builtin(__builtin_amdgcn_fdot2)
#define HAVE_FDOT2 1
#endif
#endif

__device__ __forceinline__ float fdot2(hf2 a, hf2 b, float c) {
#ifdef HAVE_FDOT2
    return __builtin_amdgcn_fdot2(a, b, c, false);
#else
    return fmaf((float)a.x, (float)b.x, fmaf((float)a.y, (float)b.y, c));
#endif
}

__global__ void __launch_bounds__(256) hist_proj1_kernel(
        const int* __restrict__ dst, int* __restrict__ count, int* __restrict__ rank,
        const float* __restrict__ x, const float* __restrict__ pos,
        const float* __restrict__ W1_src, const float* __restrict__ W1_val,
        const float* __restrict__ W1_pos,
        __half2* __restrict__ g1, int N, int E) {
    int gtid = blockIdx.x * 256 + threadIdx.x;
    int gsz = gridDim.x * 256;
    for (int e = gtid; e < E; e += gsz)
        rank[e] = atomicAdd(&count[dst[e]], 1);
    for (int t = gtid; t < N * 64; t += gsz) {
        int node = t >> 6, c = t & 63;
        float x0 = x[node * 3 + 0], x1 = x[node * 3 + 1], x2 = x[node * 3 + 2];
        float p0 = pos[node * 3 + 0], p1 = pos[node * 3 + 1], p2 = pos[node * 3 + 2];
        float as = fmaf(x0, W1_src[c], fmaf(x1, W1_src[64 + c], x2 * W1_src[128 + c]));
        float vv = fmaf(x0, W1_val[c], fmaf(x1, W1_val[64 + c], x2 * W1_val[128 + c]));
        float cc = fmaf(p0, W1_pos[c], fmaf(p1, W1_pos[64 + c], p2 * W1_pos[128 + c]));
        g1[t] = __floats2half2_rn((as + cc) * LOG2E, vv - cc);
    }
}

// Single-kernel scan: block b redundantly reduces count[0 .. b*1024) for its
// base (<=49K ints from L2), then emits its 1024-chunk's exclusive prefix.
__global__ void __launch_bounds__(256) scan_kernel(
        const int* __restrict__ count, int* __restrict__ offsets, int n, int nsb) {
    __shared__ int red[4];
    __shared__ int wpre[4];
    int tid = threadIdx.x, lane = tid & 63, wid = tid >> 6;
    int lim = blockIdx.x * 1024;
    int s = 0;
    for (int i = tid * 4; i < lim; i += 1024) {
        int4 c = *(const int4*)&count[i];
        s += c.x + c.y + c.z + c.w;
    }
    #pragma unroll
    for (int off = 32; off >= 1; off >>= 1) s += __shfl_down(s, off);
    if (lane == 0) red[wid] = s;
    __syncthreads();
    int base = red[0] + red[1] + red[2] + red[3];

    int b4 = lim + tid * 4;
    int4 c = make_int4(0, 0, 0, 0);
    if (b4 + 3 < n) {
        c = *(const int4*)&count[b4];
    } else {
        if (b4 + 0 < n) c.x = count[b4 + 0];
        if (b4 + 1 < n) c.y = count[b4 + 1];
        if (b4 + 2 < n) c.z = count[b4 + 2];
    }
    int tsum = c.x + c.y + c.z + c.w;
    int inc = tsum;
    #pragma unroll
    for (int off = 1; off < 64; off <<= 1) {
        int t2 = __shfl_up(inc, off);
        if (lane >= off) inc += t2;
    }
    if (lane == 63) wpre[wid] = inc;
    __syncthreads();
    int wbase = 0;
    for (int q = 0; q < wid; ++q) wbase += wpre[q];
    int excl = base + wbase + (inc - tsum);
    if (b4 + 0 < n) offsets[b4 + 0] = excl;
    if (b4 + 1 < n) offsets[b4 + 1] = excl + c.x;
    if (b4 + 2 < n) offsets[b4 + 2] = excl + c.x + c.y;
    if (b4 + 3 < n) offsets[b4 + 3] = excl + c.x + c.y + c.z;
    if ((int)blockIdx.x == nsb - 1 && tid == 0)
        offsets[n] = base + wpre[0] + wpre[1] + wpre[2] + wpre[3];
}

__global__ void __launch_bounds__(256) scatter_kernel(
        const int* __restrict__ src, const int* __restrict__ dst,
        const int* __restrict__ rank, const int* __restrict__ offsets,
        int* __restrict__ sorted_src, int E) {
    int e = blockIdx.x * 256 + threadIdx.x;
    if (e < E) sorted_src[offsets[dst[e]] + rank[e]] = src[e];
}

__device__ __forceinline__ void eacc(float d2, __half2 gh, float& s, float& nvv) {
    float ax = __low2float(gh);    // (a_src + c) * log2e
    float vv = __high2float(gh);   // v - c
    float ev = exp2f(d2 - ax);     // bare v_exp_f32
    s += ev;
    nvv = fmaf(ev, vv, nvv);       // dv folded out: num = nvv + dv*s
}

// Segment softmax + weighted sum for one node; 8-deep pipelined gathers.
// Returns relu((nvv + dv*s) / (s+eps)).
__device__ __forceinline__ float edge_node(
        int node, int laneoff,
        const int* __restrict__ offsets, const int* __restrict__ ss,
        const char* __restrict__ gbase, float d2, float dv) {
    int beg = offsets[node], end = offsets[node + 1];
    float s0 = 0.f, n0 = 0.f, s1 = 0.f, n1 = 0.f;
    int e = beg;
    int aligned = min((beg + 3) & ~3, end);    // peel to 16B alignment
    for (; e < aligned; ++e) {
        int i0 = __builtin_amdgcn_readfirstlane(ss[e]);
        __half2 g0 = *(const __half2*)(gbase + (((size_t)(unsigned)i0) << 8) + laneoff);
        eacc(d2, g0, s0, n0);
    }
    for (; e + 8 <= end; e += 8) {
        int4 ia = *(const int4*)(ss + e);
        int4 ib = *(const int4*)(ss + e + 4);
        int i0 = __builtin_amdgcn_readfirstlane(ia.x);
        int i1 = __builtin_amdgcn_readfirstlane(ia.y);
        int i2 = __builtin_amdgcn_readfirstlane(ia.z);
        int i3 = __builtin_amdgcn_readfirstlane(ia.w);
        int i4 = __builtin_amdgcn_readfirstlane(ib.x);
        int i5 = __builtin_amdgcn_readfirstlane(ib.y);
        int i6 = __builtin_amdgcn_readfirstlane(ib.z);
        int i7 = __builtin_amdgcn_readfirstlane(ib.w);
        __half2 g0 = *(const __half2*)(gbase + (((size_t)(unsigned)i0) << 8) + laneoff);
        __half2 g1 = *(const __half2*)(gbase + (((size_t)(unsigned)i1) << 8) + laneoff);
        __half2 g2 = *(const __half2*)(gbase + (((size_t)(unsigned)i2) << 8) + laneoff);
        __half2 g3 = *(const __half2*)(gbase + (((size_t)(unsigned)i3) << 8) + laneoff);
        __half2 g4 = *(const __half2*)(gbase + (((size_t)(unsigned)i4) << 8) + laneoff);
        __half2 g5 = *(const __half2*)(gbase + (((size_t)(unsigned)i5) << 8) + laneoff);
        __half2 g6 = *(const __half2*)(gbase + (((size_t)(unsigned)i6) << 8) + laneoff);
        __half2 g7 = *(const __half2*)(gbase + (((size_t)(unsigned)i7) << 8) + laneoff);
        eacc(d2, g0, s0, n0);
        eacc(d2, g1, s1, n1);
        eacc(d2, g2, s0, n0);
        eacc(d2, g3, s1, n1);
        eacc(d2, g4, s0, n0);
        eacc(d2, g5, s1, n1);
        eacc(d2, g6, s0, n0);
        eacc(d2, g7, s1, n1);
    }
    for (; e + 4 <= end; e += 4) {
        int4 ia = *(const int4*)(ss + e);
        int i0 = __builtin_amdgcn_readfirstlane(ia.x);
        int i1 = __builtin_amdgcn_readfirstlane(ia.y);
        int i2 = __builtin_amdgcn_readfirstlane(ia.z);
        int i3 = __builtin_amdgcn_readfirstlane(ia.w);
        __half2 g0 = *(const __half2*)(gbase + (((size_t)(unsigned)i0) << 8) + laneoff);
        __half2 g1 = *(const __half2*)(gbase + (((size_t)(unsigned)i1) << 8) + laneoff);
        __half2 g2 = *(const __half2*)(gbase + (((size_t)(unsigned)i2) << 8) + laneoff);
        __half2 g3 = *(const __half2*)(gbase + (((size_t)(unsigned)i3) << 8) + laneoff);
        eacc(d2, g0, s0, n0);
        eacc(d2, g1, s1, n1);
        eacc(d2, g2, s0, n0);
        eacc(d2, g3, s1, n1);
    }
    for (; e < end; ++e) {
        int i0 = __builtin_amdgcn_readfirstlane(ss[e]);
        __half2 g0 = *(const __half2*)(gbase + (((size_t)(unsigned)i0) << 8) + laneoff);
        eacc(d2, g0, s0, n0);
    }
    float s = s0 + s1;
    float num = fmaf(dv, s, n0 + n1);
    return fmaxf(num / (s + 1e-16f), 0.f);
}

// E1 + proj2 fused, grid-strided. proj2 dot via v_dot2_f32_f16:
// h packed to LDS as 32 half2 (broadcast reads), W2 staged as k-paired
// (src-pair, val-pair) 8B entries -> 1 ds_read_b64 + 1 b32 + 2 fdot2 per kk.
__global__ void __launch_bounds__(256, 8) e1p2_kernel(
        const float* __restrict__ pos,
        const int* __restrict__ offsets, const int* __restrict__ sorted_src,
        const __half2* __restrict__ g1,
        const float* __restrict__ W1_pos, const float* __restrict__ b1_pos,
        const float* __restrict__ W2_src, const float* __restrict__ W2_val,
        const float* __restrict__ W2_pos,
        __half2* __restrict__ g2, int N) {
    __shared__ uint2 W4[2048];        // [kk][c]: (src k-pair, val k-pair), 16KB
    __shared__ __half hsh[4][64];
    int tid = threadIdx.x, lane = tid & 63, wid = tid >> 6;
    for (int idx = tid; idx < 2048; idx += 256) {
        int kk = idx >> 6, c = idx & 63;
        H2U ws, wv;
        ws.hh = __floats2half2_rn(W2_src[(2 * kk) * 64 + c], W2_src[(2 * kk + 1) * 64 + c]);
        wv.hh = __floats2half2_rn(W2_val[(2 * kk) * 64 + c], W2_val[(2 * kk + 1) * 64 + c]);
        W4[idx] = make_uint2(ws.u, wv.u);
    }
    __syncthreads();

    float w1p0 = W1_pos[lane], w1p1 = W1_pos[64 + lane], w1p2 = W1_pos[128 + lane];
    float bp1 = b1_pos[lane];
    float w2p0 = W2_pos[lane], w2p1 = W2_pos[64 + lane], w2p2 = W2_pos[128 + lane];
    int laneoff = lane * 4;
    int nwav = gridDim.x * 4;

    for (int node = blockIdx.x * 4 + wid; node < N; node += nwav) {
        float p0 = pos[node * 3 + 0], p1 = pos[node * 3 + 1], p2 = pos[node * 3 + 2];
        float dpos = fmaf(p0, w1p0, fmaf(p1, w1p1, p2 * w1p2));
        float hval = edge_node(node, laneoff, offsets, sorted_src,
                               (const char*)g1, dpos * LOG2E, dpos + bp1);
        hsh[wid][lane] = __float2half(hval);   // same-wave publish (ds_write_b16)
        const hf2* h2 = (const hf2*)hsh[wid];
        float as = 0.f, vv = 0.f;
        #pragma unroll 8
        for (int kk = 0; kk < 32; ++kk) {
            hf2 hk = h2[kk];                   // 4B broadcast read
            WPack wp; wp.u2 = W4[kk * 64 + lane];   // ds_read_b64
            H2U a, b; a.u = wp.w.s; b.u = wp.w.v;
            as = fdot2(hk, a.hf, as);
            vv = fdot2(hk, b.hf, vv);
        }
        float cc = fmaf(p0, w2p0, fmaf(p1, w2p1, p2 * w2p2));
        g2[node * 64 + lane] = __floats2half2_rn((as + cc) * LOG2E, vv - cc);
    }
}

// E2 + fused relu/fc1/relu/fc2 head, grid-strided, fc1 via fdot2.
// lane l -> out channel l&31, k-half (l>>5)*16 pairs; combined via shfl(32).
__global__ void __launch_bounds__(256, 8) e2head_kernel(
        const float* __restrict__ pos,
        const int* __restrict__ offsets, const int* __restrict__ sorted_src,
        const __half2* __restrict__ g2,
        const float* __restrict__ W2_pos, const float* __restrict__ b2_pos,
        const float* __restrict__ Wfc1, const float* __restrict__ bfc1,
        const float* __restrict__ Wfc2, const float* __restrict__ bfc2,
        float* __restrict__ out, int N) {
    __shared__ unsigned Wf2[1024];    // [kk][c] fc1 k-pairs as half2 bits, 4KB
    __shared__ __half hsh[4][64];
    int tid = threadIdx.x, lane = tid & 63, wid = tid >> 6;
    for (int idx = tid; idx < 1024; idx += 256) {
        int kk = idx >> 5, c = idx & 31;
        H2U w;
        w.hh = __floats2half2_rn(Wfc1[(2 * kk) * 32 + c], Wfc1[(2 * kk + 1) * 32 + c]);
        Wf2[idx] = w.u;
    }
    __syncthreads();

    float wp0 = W2_pos[lane], wp1 = W2_pos[64 + lane], wp2 = W2_pos[128 + lane];
    float bp = b2_pos[lane];
    int c = lane & 31, khb = (lane >> 5) * 16;
    float bfc1c = bfc1[c], wfc2c = Wfc2[c], bias2 = bfc2[0];
    int laneoff = lane * 4;
    int nwav = gridDim.x * 4;

    for (int node = blockIdx.x * 4 + wid; node < N; node += nwav) {
        float p0 = pos[node * 3 + 0], p1 = pos[node * 3 + 1], p2 = pos[node * 3 + 2];
        float dpos = fmaf(p0, wp0, fmaf(p1, wp1, p2 * wp2));
        float hval = edge_node(node, laneoff, offsets, sorted_src,
                               (const char*)g2, dpos * LOG2E, dpos + bp);
        hsh[wid][lane] = __float2half(hval);   // all-lane same-wave publish
        const hf2* h2 = (const hf2*)hsh[wid];
        float t2 = 0.f;
        #pragma unroll 8
        for (int j = 0; j < 16; ++j) {
            hf2 hk = h2[khb + j];              // 4B broadcast read
            H2U w; w.u = Wf2[(khb + j) * 32 + c];
            t2 = fdot2(hk, w.hf, t2);
        }
        t2 += __shfl_down(t2, 32);             // all lanes execute
        t2 = fmaxf(t2 + bfc1c, 0.f) * wfc2c;
        t2 = (lane < 32) ? t2 : 0.f;
        #pragma unroll
        for (int off = 16; off >= 1; off >>= 1) t2 += __shfl_down(t2, off);
        if (lane == 0) out[node] = t2 + bias2;
    }
}

extern "C" void kernel_launch(void* const* d_in, const int* in_sizes, int n_in,
                              void* d_out, int out_size, void* d_ws, size_t ws_size,
                              hipStream_t stream) {
    const float* x   = (const float*)d_in[0];
    const float* pos = (const float*)d_in[1];
    const int* eidx  = (const int*)d_in[2];
    const float* W1_src = (const float*)d_in[4];
    // d_in[5] = W1_dst: cancels in softmax
    const float* W1_val = (const float*)d_in[6];
    const float* W1_pos = (const float*)d_in[7];
    const float* b1_pos = (const float*)d_in[8];
    const float* W2_src = (const float*)d_in[9];
    // d_in[10] = W2_dst: cancels in softmax
    const float* W2_val = (const float*)d_in[11];
    const float* W2_pos = (const float*)d_in[12];
    const float* b2_pos = (const float*)d_in[13];
    const float* W_fc1  = (const float*)d_in[14];
    const float* b_fc1  = (const float*)d_in[15];
    const float* W_fc2  = (const float*)d_in[16];
    const float* b_fc2  = (const float*)d_in[17];

    const int N = in_sizes[0] / 3;
    const int E = in_sizes[2] / 2;
    const int* src = eidx;
    const int* dst = eidx + E;
    const int nsb = (N + 1023) / 1024;   // 49 for N=50K

    char* w = (char*)d_ws;
    auto carve = [&](size_t bytes) -> void* {
        void* p = (void*)w;
        w += (bytes + 255) & ~size_t(255);
        return p;
    };
    int*     count      = (int*)carve((size_t)N * 4);
    int*     offsets    = (int*)carve((size_t)(N + 1) * 4);
    int*     rank       = (int*)carve((size_t)E * 4);
    int*     sorted_src = (int*)carve((size_t)E * 4);
    __half2* g1         = (__half2*)carve((size_t)N * 64 * 4);
    __half2* g2         = (__half2*)carve((size_t)N * 64 * 4);

    hipMemsetAsync(count, 0, (size_t)N * 4, stream);
    hist_proj1_kernel<<<(N * 64 + 255) / 256, 256, 0, stream>>>(
        dst, count, rank, x, pos, W1_src, W1_val, W1_pos, g1, N, E);
    scan_kernel<<<nsb, 256, 0, stream>>>(count, offsets, N, nsb);
    scatter_kernel<<<(E + 255) / 256, 256, 0, stream>>>(src, dst, rank, offsets,
                                                        sorted_src, E);
    e1p2_kernel<<<2048, 256, 0, stream>>>(
        pos, offsets, sorted_src, g1, W1_pos, b1_pos, W2_src, W2_val, W2_pos, g2, N);
    e2head_kernel<<<2048, 256, 0, stream>>>(
        pos, offsets, sorted_src, g2, W2_pos, b2_pos,
        W_fc1, b_fc1, W_fc2, b_fc2, (float*)d_out, N);
}